// Round 2
// baseline (554.508 us; speedup 1.0000x reference)
//
#include <hip/hip_runtime.h>

#define VQ_K 512
#define VQ_D 64
#define VQ_N (32 * 64 * 64)   // B*H*W = 131072
#define CH_STRIDE 4096        // H*W
#define B_STRIDE  262144      // C*H*W
#define KSPLIT 4
#define KPW (VQ_K / KSPLIT)   // 128 codes per wave

// Pre-pass: squared norms of codebook rows into workspace.
__global__ void cb_sqr_kernel(const float* __restrict__ cb,
                              float* __restrict__ cbsq) {
    int k = blockIdx.x * blockDim.x + threadIdx.x;
    if (k < VQ_K) {
        float s = 0.f;
        #pragma unroll
        for (int d = 0; d < VQ_D; ++d) {
            float v = cb[k * VQ_D + d];
            s = fmaf(v, v, s);
        }
        cbsq[k] = s;
    }
}

// Block = 256 threads = 64 positions x 4 k-groups.
// Wave w scans codes [w*128, w*128+128) for its 64 positions; LDS reduce
// combines the 4 per-wave candidates in ascending-k order (strict <) to
// match np.argmin first-occurrence tie-breaking.
// __launch_bounds__(256,4): VGPR cap 128 so v[64] stays in registers
// (R1: default heuristic capped at 56 VGPR and sank x loads into the loop).
__global__ __launch_bounds__(256, 4) void vq_argmin_kernel(
        const float* __restrict__ x,
        const float* __restrict__ cb,
        const float* __restrict__ cbsq,
        int* __restrict__ out) {
    int t   = threadIdx.x;
    int pos = t & 63;         // position within block
    int w   = t >> 6;         // wave id = k-group
    int n   = blockIdx.x * 64 + pos;
    int b   = n >> 12;        // / 4096 (64 divides 4096: whole block same batch)
    int p   = n & 4095;       // h*64 + w
    const float* xb = x + b * B_STRIDE + p;

    // Load the 64-dim vector once into VGPRs (coalesced: consecutive lanes ->
    // consecutive addresses per channel; 4 waves re-read same 16KB via L1).
    float v[VQ_D];
    #pragma unroll
    for (int d = 0; d < VQ_D; ++d) v[d] = xb[d * CH_STRIDE];

    // ||x||^2 — kept so the fp32 distance expression matches the reference
    // association exactly (R1 matched np with absmax 0.0).
    float s0 = 0.f, s1 = 0.f, s2 = 0.f, s3 = 0.f;
    #pragma unroll
    for (int d = 0; d < VQ_D; d += 4) {
        s0 = fmaf(v[d + 0], v[d + 0], s0);
        s1 = fmaf(v[d + 1], v[d + 1], s1);
        s2 = fmaf(v[d + 2], v[d + 2], s2);
        s3 = fmaf(v[d + 3], v[d + 3], s3);
    }
    float insq = (s0 + s1) + (s2 + s3);

    float best = 3.4e38f;
    int bi = 0;
    int k0 = w * KPW;
    for (int k = k0; k < k0 + KPW; ++k) {
        const float* row = cb + k * VQ_D;   // wave-uniform -> s_load
        float d0 = 0.f, d1 = 0.f, d2 = 0.f, d3 = 0.f;
        #pragma unroll
        for (int d = 0; d < VQ_D; d += 4) {
            d0 = fmaf(v[d + 0], row[d + 0], d0);
            d1 = fmaf(v[d + 1], row[d + 1], d1);
            d2 = fmaf(v[d + 2], row[d + 2], d2);
            d3 = fmaf(v[d + 3], row[d + 3], d3);
        }
        float dot  = (d0 + d1) + (d2 + d3);
        float dist = (insq + cbsq[k]) - 2.f * dot;
        if (dist < best) { best = dist; bi = k; }   // strict <: lowest k on ties
    }

    // Cross-wave argmin reduce via LDS (2 KB), ascending k-group order.
    __shared__ float sbest[KSPLIT][64];
    __shared__ int   sbi[KSPLIT][64];
    sbest[w][pos] = best;
    sbi[w][pos]   = bi;
    __syncthreads();
    if (t < 64) {
        float bb = sbest[0][t];
        int   ii = sbi[0][t];
        #pragma unroll
        for (int j = 1; j < KSPLIT; ++j) {
            float c = sbest[j][t];
            if (c < bb) { bb = c; ii = sbi[j][t]; }
        }
        out[blockIdx.x * 64 + t] = ii;
    }
}

extern "C" void kernel_launch(void* const* d_in, const int* in_sizes, int n_in,
                              void* d_out, int out_size, void* d_ws, size_t ws_size,
                              hipStream_t stream) {
    const float* x  = (const float*)d_in[0];   // [32,64,64,64] fp32
    const float* cb = (const float*)d_in[1];   // [512,64] fp32
    int* out = (int*)d_out;                    // [32,64,64] int32
    float* cbsq = (float*)d_ws;                // 512 floats scratch

    cb_sqr_kernel<<<1, VQ_K, 0, stream>>>(cb, cbsq);
    vq_argmin_kernel<<<VQ_N / 64, 256, 0, stream>>>(x, cb, cbsq, out);
}

// Round 3
// 181.126 us; speedup vs baseline: 3.0615x; 3.0615x over previous
//
#include <hip/hip_runtime.h>

#define VQ_K 512
#define VQ_D 64
#define VQ_N (32 * 64 * 64)   // B*H*W = 131072
#define CH_STRIDE 4096        // H*W
#define B_STRIDE  262144      // C*H*W
#define KSPLIT 4
#define KPW (VQ_K / KSPLIT)   // 128 codes per wave

// Pre-pass: squared norms of codebook rows into workspace.
__global__ void cb_sqr_kernel(const float* __restrict__ cb,
                              float* __restrict__ cbsq) {
    int k = blockIdx.x * blockDim.x + threadIdx.x;
    if (k < VQ_K) {
        float s = 0.f;
        #pragma unroll
        for (int d = 0; d < VQ_D; ++d) {
            float v = cb[k * VQ_D + d];
            s = fmaf(v, v, s);
        }
        cbsq[k] = s;
    }
}

// Block = 256 threads = 64 positions x 4 k-groups (wave w scans codes
// [w*128, w*128+128)). Two fixes vs R2:
//  (1) w via readfirstlane -> provably wave-uniform -> codebook row loads go
//      through the SCALAR path (R2: SGPR=32 showed vector loads; R1: SGPR=112).
//  (2) asm pin of v[64] -> loads cannot be rematerialized into the k-loop
//      (R1/R2: VGPR=56/48 showed x was re-read from cache every k-iter).
__global__ __launch_bounds__(256, 4) void vq_argmin_kernel(
        const float* __restrict__ x,
        const float* __restrict__ cb,
        const float* __restrict__ cbsq,
        int* __restrict__ out) {
    int t   = threadIdx.x;
    int pos = t & 63;                                     // position in block
    int w   = __builtin_amdgcn_readfirstlane(t >> 6);     // wave id, uniform
    int n   = blockIdx.x * 64 + pos;
    int b   = n >> 12;        // / 4096 (64 | 4096: whole block in same batch)
    int p   = n & 4095;       // h*64 + w
    const float* xb = x + b * B_STRIDE + p;

    // Load the 64-dim vector once (coalesced across lanes per channel) ...
    float v[VQ_D];
    #pragma unroll
    for (int d = 0; d < VQ_D; ++d) v[d] = xb[d * CH_STRIDE];
    // ... and pin it in VGPRs: opaque asm output can't be rematerialized,
    // so the k-loop below is pure VALU with no vector-memory traffic.
    #pragma unroll
    for (int d = 0; d < VQ_D; ++d) asm volatile("" : "+v"(v[d]));

    // ||x||^2 in fp32, 4 accumulators (same association as R1, absmax 0.0).
    float s0 = 0.f, s1 = 0.f, s2 = 0.f, s3 = 0.f;
    #pragma unroll
    for (int d = 0; d < VQ_D; d += 4) {
        s0 = fmaf(v[d + 0], v[d + 0], s0);
        s1 = fmaf(v[d + 1], v[d + 1], s1);
        s2 = fmaf(v[d + 2], v[d + 2], s2);
        s3 = fmaf(v[d + 3], v[d + 3], s3);
    }
    float insq = (s0 + s1) + (s2 + s3);

    float best = 3.4e38f;
    int bi = 0;
    const float* rowbase = cb + w * (KPW * VQ_D);
    const float* sqbase  = cbsq + w * KPW;
    for (int kk = 0; kk < KPW; ++kk) {
        const float* row = rowbase + kk * VQ_D;   // uniform -> s_load_dwordx16
        float d0 = 0.f, d1 = 0.f, d2 = 0.f, d3 = 0.f;
        #pragma unroll
        for (int d = 0; d < VQ_D; d += 4) {
            d0 = fmaf(v[d + 0], row[d + 0], d0);
            d1 = fmaf(v[d + 1], row[d + 1], d1);
            d2 = fmaf(v[d + 2], row[d + 2], d2);
            d3 = fmaf(v[d + 3], row[d + 3], d3);
        }
        float dot  = (d0 + d1) + (d2 + d3);
        float dist = (insq + sqbase[kk]) - 2.f * dot;
        if (dist < best) { best = dist; bi = w * KPW + kk; }  // strict <
    }

    // Cross-wave argmin reduce via LDS (2 KB), ascending k-group order
    // with strict < preserves np.argmin first-occurrence tie-breaking.
    __shared__ float sbest[KSPLIT][64];
    __shared__ int   sbi[KSPLIT][64];
    sbest[w][pos] = best;
    sbi[w][pos]   = bi;
    __syncthreads();
    if (t < 64) {
        float bb = sbest[0][t];
        int   ii = sbi[0][t];
        #pragma unroll
        for (int j = 1; j < KSPLIT; ++j) {
            float c = sbest[j][t];
            if (c < bb) { bb = c; ii = sbi[j][t]; }
        }
        out[blockIdx.x * 64 + t] = ii;
    }
}

extern "C" void kernel_launch(void* const* d_in, const int* in_sizes, int n_in,
                              void* d_out, int out_size, void* d_ws, size_t ws_size,
                              hipStream_t stream) {
    const float* x  = (const float*)d_in[0];   // [32,64,64,64] fp32
    const float* cb = (const float*)d_in[1];   // [512,64] fp32
    int* out = (int*)d_out;                    // [32,64,64] int32
    float* cbsq = (float*)d_ws;                // 512 floats scratch

    cb_sqr_kernel<<<1, VQ_K, 0, stream>>>(cb, cbsq);
    vq_argmin_kernel<<<VQ_N / 64, 256, 0, stream>>>(x, cb, cbsq, out);
}

// Round 4
// 178.128 us; speedup vs baseline: 3.1130x; 1.0168x over previous
//
#include <hip/hip_runtime.h>

#define VQ_K 512
#define VQ_D 64
#define VQ_N (32 * 64 * 64)   // B*H*W = 131072
#define CH_STRIDE 4096        // H*W
#define B_STRIDE  262144      // C*H*W
#define KSPLIT 4
#define KPW (VQ_K / KSPLIT)   // 128 codes per wave

typedef float f32x8 __attribute__((ext_vector_type(8)));

// Pre-pass: squared norms of codebook rows into workspace.
__global__ void cb_sqr_kernel(const float* __restrict__ cb,
                              float* __restrict__ cbsq) {
    int k = blockIdx.x * blockDim.x + threadIdx.x;
    if (k < VQ_K) {
        float s = 0.f;
        #pragma unroll
        for (int d = 0; d < VQ_D; ++d) {
            float v = cb[k * VQ_D + d];
            s = fmaf(v, v, s);
        }
        cbsq[k] = s;
    }
}

// Block = 256 threads = 64 positions x 4 k-groups (wave w scans codes
// [w*128, w*128+128)).
// R3 post-mortem: VGPR=48 + dur matching the L2 spill-reload roofline showed
// the RA spilled the 64 pinned x-values to scratch. Fixes:
//  - amdgpu_waves_per_eu(3): VGPR budget 170 >> ~90 needed, so keeping x
//    resident is strictly cheaper than spilling.
//  - single asm pin of 8 x float8 tuples (not 64 scalar pins) — one clean
//    forcing point for the RA, values non-rematerializable afterwards.
__global__
__attribute__((amdgpu_flat_work_group_size(256, 256), amdgpu_waves_per_eu(3)))
void vq_argmin_kernel(
        const float* __restrict__ x,
        const float* __restrict__ cb,
        const float* __restrict__ cbsq,
        int* __restrict__ out) {
    int t   = threadIdx.x;
    int pos = t & 63;                                     // position in block
    int w   = __builtin_amdgcn_readfirstlane(t >> 6);     // wave id, uniform
    int n   = blockIdx.x * 64 + pos;
    int b   = n >> 12;        // / 4096 (64 | 4096: whole block in same batch)
    int p   = n & 4095;       // h*64 + w
    const float* xb = x + b * B_STRIDE + p;

    // Load the 64-dim vector once (coalesced across lanes per channel) into
    // 8 float8 tuples, then pin them in VGPRs with ONE opaque asm statement.
    f32x8 vv[8];
    #pragma unroll
    for (int c = 0; c < 8; ++c) {
        #pragma unroll
        for (int j = 0; j < 8; ++j)
            vv[c][j] = xb[(c * 8 + j) * CH_STRIDE];
    }
    asm volatile("" : "+v"(vv[0]), "+v"(vv[1]), "+v"(vv[2]), "+v"(vv[3]),
                      "+v"(vv[4]), "+v"(vv[5]), "+v"(vv[6]), "+v"(vv[7]));

    // ||x||^2 in fp32, 4 accumulators (same association as R1-R3, absmax 0.0).
    float s0 = 0.f, s1 = 0.f, s2 = 0.f, s3 = 0.f;
    #pragma unroll
    for (int c = 0; c < 8; ++c) {
        s0 = fmaf(vv[c][0], vv[c][0], s0);
        s1 = fmaf(vv[c][1], vv[c][1], s1);
        s2 = fmaf(vv[c][2], vv[c][2], s2);
        s3 = fmaf(vv[c][3], vv[c][3], s3);
        s0 = fmaf(vv[c][4], vv[c][4], s0);
        s1 = fmaf(vv[c][5], vv[c][5], s1);
        s2 = fmaf(vv[c][6], vv[c][6], s2);
        s3 = fmaf(vv[c][7], vv[c][7], s3);
    }
    float insq = (s0 + s1) + (s2 + s3);

    float best = 3.4e38f;
    int bi = 0;
    const float* rowbase = cb + w * (KPW * VQ_D);
    const float* sqbase  = cbsq + w * KPW;
    for (int kk = 0; kk < KPW; ++kk) {
        const float* row = rowbase + kk * VQ_D;   // uniform -> s_load_dwordx16
        float d0 = 0.f, d1 = 0.f, d2 = 0.f, d3 = 0.f;
        #pragma unroll
        for (int c = 0; c < 8; ++c) {
            d0 = fmaf(vv[c][0], row[c * 8 + 0], d0);
            d1 = fmaf(vv[c][1], row[c * 8 + 1], d1);
            d2 = fmaf(vv[c][2], row[c * 8 + 2], d2);
            d3 = fmaf(vv[c][3], row[c * 8 + 3], d3);
            d0 = fmaf(vv[c][4], row[c * 8 + 4], d0);
            d1 = fmaf(vv[c][5], row[c * 8 + 5], d1);
            d2 = fmaf(vv[c][6], row[c * 8 + 6], d2);
            d3 = fmaf(vv[c][7], row[c * 8 + 7], d3);
        }
        float dot  = (d0 + d1) + (d2 + d3);
        float dist = (insq + sqbase[kk]) - 2.f * dot;
        if (dist < best) { best = dist; bi = w * KPW + kk; }  // strict <
    }

    // Cross-wave argmin reduce via LDS (2 KB), ascending k-group order
    // with strict < preserves np.argmin first-occurrence tie-breaking.
    __shared__ float sbest[KSPLIT][64];
    __shared__ int   sbi[KSPLIT][64];
    sbest[w][pos] = best;
    sbi[w][pos]   = bi;
    __syncthreads();
    if (t < 64) {
        float bb = sbest[0][t];
        int   ii = sbi[0][t];
        #pragma unroll
        for (int j = 1; j < KSPLIT; ++j) {
            float c = sbest[j][t];
            if (c < bb) { bb = c; ii = sbi[j][t]; }
        }
        out[blockIdx.x * 64 + t] = ii;
    }
}

extern "C" void kernel_launch(void* const* d_in, const int* in_sizes, int n_in,
                              void* d_out, int out_size, void* d_ws, size_t ws_size,
                              hipStream_t stream) {
    const float* x  = (const float*)d_in[0];   // [32,64,64,64] fp32
    const float* cb = (const float*)d_in[1];   // [512,64] fp32
    int* out = (int*)d_out;                    // [32,64,64] int32
    float* cbsq = (float*)d_ws;                // 512 floats scratch

    cb_sqr_kernel<<<1, VQ_K, 0, stream>>>(cb, cbsq);
    vq_argmin_kernel<<<VQ_N / 64, 256, 0, stream>>>(x, cb, cbsq, out);
}